// Round 1
// baseline (141.948 us; speedup 1.0000x reference)
//
#include <hip/hip_runtime.h>
#include <math.h>

// Problem constants (match reference)
constexpr int N_IN  = 4096;
constexpr int N_REC = 4096;
constexpr int NCHUNK = 64;              // split-K chunks for the GEMV
constexpr int ROWS   = N_IN / NCHUNK;   // 64 rows per chunk

// ---------------------------------------------------------------------------
// K1: partial GEMV  isc_partial[chunk][col] = sum_{r in chunk} x[r]*w[r][col]
// grid = (4 col-blocks, 64 chunks), block = 256 threads, 4 cols per thread.
// Reads w_in once (64 MB) with float4 coalesced loads.
// ---------------------------------------------------------------------------
__global__ __launch_bounds__(256) void k1_gemv_partial(
    const float* __restrict__ x, const float* __restrict__ w,
    float* __restrict__ partials)
{
    const int chunk = blockIdx.y;
    const int c0 = (blockIdx.x * 256 + threadIdx.x) * 4;

    __shared__ float xs[ROWS];
    if (threadIdx.x < ROWS) xs[threadIdx.x] = x[chunk * ROWS + threadIdx.x];
    __syncthreads();

    const float* wp = w + (size_t)chunk * ROWS * N_REC + c0;
    float4 acc = {0.f, 0.f, 0.f, 0.f};
#pragma unroll 8
    for (int r = 0; r < ROWS; ++r) {
        float4 wv = *(const float4*)(wp + (size_t)r * N_REC);
        const float xr = xs[r];
        acc.x = fmaf(xr, wv.x, acc.x);
        acc.y = fmaf(xr, wv.y, acc.y);
        acc.z = fmaf(xr, wv.z, acc.z);
        acc.w = fmaf(xr, wv.w, acc.w);
    }
    *(float4*)(partials + (size_t)chunk * N_REC + c0) = acc;
}

// ---------------------------------------------------------------------------
// K2: reduce partials -> isc; LIF dynamics; write z/v/i outputs; per-block
// spike sums (no atomics so no ws zero-init needed). grid = 16 blocks x 256.
// ---------------------------------------------------------------------------
__global__ __launch_bounds__(256) void k2_lif(
    const float* __restrict__ partials, const float* __restrict__ v_in,
    const float* __restrict__ thr, float* __restrict__ out,
    float* __restrict__ isc, float* __restrict__ blockSums)
{
    const int col = blockIdx.x * 256 + threadIdx.x;

    float I = 0.f;
#pragma unroll 8
    for (int p = 0; p < NCHUNK; ++p) I += partials[(size_t)p * N_REC + col];
    isc[col] = I;

    const float v  = v_in[col];
    float nv = v + 0.1f * (I - v);                       // (1-decay_v) == 0.1f
    const float spk = (tanhf(nv) > thr[col]) ? 1.0f : 0.0f;
    nv = nv * (1.0f - spk);

    out[col]             = spk;   // new_z (DT = 1)
    out[N_REC + col]     = nv;    // new_v
    out[2 * N_REC + col] = nv;    // new_i

    // block spike-sum: wave shuffle reduce then LDS combine
    float s = spk;
#pragma unroll
    for (int o = 32; o > 0; o >>= 1) s += __shfl_down(s, o, 64);
    __shared__ float wsum[4];
    const int lane = threadIdx.x & 63, wid = threadIdx.x >> 6;
    if (lane == 0) wsum[wid] = s;
    __syncthreads();
    if (threadIdx.x == 0)
        blockSums[blockIdx.x] = wsum[0] + wsum[1] + wsum[2] + wsum[3];
}

// ---------------------------------------------------------------------------
// K3: scalar epilogue — pop_activity and surprise.
// ---------------------------------------------------------------------------
__global__ void k3_scalar(
    const float* __restrict__ blockSums, const float* __restrict__ A,
    float* __restrict__ out_pop, float* __restrict__ surprise)
{
    if (threadIdx.x == 0) {
        float s = 0.f;
#pragma unroll
        for (int i = 0; i < 16; ++i) s += blockSums[i];
        const float a   = A[0];
        const float pop = a + (1.0f / 50.0f) * (s - a);
        out_pop[0] = pop;
        const float x = pop * 0.5f;                       // / A0_CONST (=2)
        const float t = (x > 0.0f) ? tanhf(x) : 0.0f;
        float sur = 0.00157f * t;
        if (x > 0.2206f) sur += 0.05749f * t;
        surprise[0] = sur;
    }
}

// ---------------------------------------------------------------------------
// K4: weight update. new_w[k][i] = w[k][i]                  (k < 2048)
//                    clip(w[k][i] - sur*isc[i]*x[k])        (k >= 2048)
// clip: min(.,0) for i<2048, max(.,0) for i>=2048.
// Output base is d_out + 12289 floats (odd) -> only 4B aligned, so stores
// are 4 coalesced dwords per thread; loads are aligned float4.
// grid = 16384 blocks x 256 threads, 4 elements/thread.
// ---------------------------------------------------------------------------
__global__ __launch_bounds__(256) void k4_wupdate(
    const float* __restrict__ w, const float* __restrict__ x,
    const float* __restrict__ isc, const float* __restrict__ surprise,
    float* __restrict__ wout)
{
    const unsigned gid = blockIdx.x * 256 + threadIdx.x;
    const int k  = gid >> 10;             // 1024 float4 per row
    const int i0 = (gid & 1023) << 2;
    const size_t off = (size_t)k * N_REC + i0;

    float4 wv = *(const float4*)(w + off);
    float4 o;
    if (k < N_IN / 2) {
        o = wv;                            // masked_input == 0 -> pure copy
    } else {
        const float coef = -surprise[0] * x[k];
        float4 iv = *(const float4*)(isc + i0);
        o.x = fmaf(coef, iv.x, wv.x);
        o.y = fmaf(coef, iv.y, wv.y);
        o.z = fmaf(coef, iv.z, wv.z);
        o.w = fmaf(coef, iv.w, wv.w);
        if (i0 < N_REC / 2) {              // clip_max = 0
            o.x = fminf(o.x, 0.f); o.y = fminf(o.y, 0.f);
            o.z = fminf(o.z, 0.f); o.w = fminf(o.w, 0.f);
        } else {                           // clip_min = 0
            o.x = fmaxf(o.x, 0.f); o.y = fmaxf(o.y, 0.f);
            o.z = fmaxf(o.z, 0.f); o.w = fmaxf(o.w, 0.f);
        }
    }
    float* wo = wout + off;
    wo[0] = o.x; wo[1] = o.y; wo[2] = o.z; wo[3] = o.w;
}

// ---------------------------------------------------------------------------
extern "C" void kernel_launch(void* const* d_in, const int* in_sizes, int n_in,
                              void* d_out, int out_size, void* d_ws, size_t ws_size,
                              hipStream_t stream)
{
    // setup_inputs order: inputs, v, i_state, z, A, w_in, thresholds
    const float* inputs = (const float*)d_in[0];
    const float* v      = (const float*)d_in[1];
    const float* A      = (const float*)d_in[4];
    const float* w_in   = (const float*)d_in[5];
    const float* thr    = (const float*)d_in[6];
    float* out = (float*)d_out;
    // out layout: z[4096] | v[4096] | i[4096] | pop[1] | w[4096*4096]

    float* partials  = (float*)d_ws;                  // 64*4096 floats (1 MB)
    float* isc       = partials + (size_t)NCHUNK * N_REC;
    float* blockSums = isc + N_REC;                   // 16 floats
    float* surprise  = blockSums + 16;                // 1 float

    k1_gemv_partial<<<dim3(4, NCHUNK), 256, 0, stream>>>(inputs, w_in, partials);
    k2_lif<<<16, 256, 0, stream>>>(partials, v, thr, out, isc, blockSums);
    k3_scalar<<<1, 64, 0, stream>>>(blockSums, A, out + 3 * N_REC, surprise);
    k4_wupdate<<<(N_IN * N_REC / 4) / 256, 256, 0, stream>>>(
        w_in, inputs, isc, surprise, out + 3 * N_REC + 1);
}